// Round 18
// baseline (152.431 us; speedup 1.0000x reference)
//
#include <hip/hip_runtime.h>
#include <math.h>

// ---------------------------------------------------------------------------
// GOTSim, phase-split for measurement: prep (adjacency planes + W planes) ->
// gnn_k (256 blocks: 3x [MFMA GEMM -> MFMA agg -> MFMA sim], sims to global)
// -> lap_k (768 x 1-wave JV LAP, R6-proven) -> final_k. 4 dispatches.
// B=256 pairs, S=32 nodes, L=3 layers, FIN=512, F=256.
// ---------------------------------------------------------------------------

#define LAP_INF 1e30f

typedef __attribute__((ext_vector_type(8))) short short8;
typedef __attribute__((ext_vector_type(4))) float f32x4;

__device__ __forceinline__ unsigned short bf16_rne(float x) {
  unsigned u = __float_as_uint(x);
  return (unsigned short)((u + 0x7fffu + ((u >> 16) & 1u)) >> 16);
}
__device__ __forceinline__ void split2(float x, unsigned short& h, unsigned short& l) {
  h = bf16_rne(x);
  l = (unsigned short)(__float_as_uint(x - __uint_as_float((unsigned)h << 16)) >> 16);
}
__device__ __forceinline__ float bf2f(unsigned short u) {
  return __uint_as_float((unsigned)u << 16);
}

// ---- prep: per-graph adjacency bf16 hi/lo planes + W bf16 planes ----------
__global__ __launch_bounds__(512) void prep_k(const int* __restrict__ eiq,
                                              const int* __restrict__ eic,
                                              const float* __restrict__ W0,
                                              const float* __restrict__ W1,
                                              const float* __restrict__ W2,
                                              unsigned short* __restrict__ adjPH,
                                              unsigned short* __restrict__ adjPL,
                                              unsigned short* __restrict__ WP,
                                              int ne) {
  const int bx = blockIdx.x;
  const int t = threadIdx.x;
  if (bx < 512) {
    __shared__ float A[1024];
    __shared__ float dinv[32];
    const int g = bx & 255, side = bx >> 8;
    const int* ei = side ? eic : eiq;
    const int half = ne >> 1;
    for (int k = t; k < 1024; k += 512) A[k] = 0.f;
    __syncthreads();
    if (t < 256) {
      int e = (t < 128) ? (g * 128 + t) : (half + g * 128 + (t - 128));
      int s = ei[e];
      int d = ei[ne + e];
      if ((d >> 5) == g)
        atomicAdd(&A[(d & 31) * 32 + (s & 31)], 1.0f);
    }
    __syncthreads();
    if (t < 32) A[t * 32 + t] += 1.0f;
    __syncthreads();
    if (t < 32) {
      float dsum = 0.f;
#pragma unroll
      for (int j = 0; j < 32; ++j) dsum += A[t * 32 + j];
      dinv[t] = rsqrtf(dsum);
    }
    __syncthreads();
    unsigned short* AH = adjPH + (size_t)(side * 256 + g) * 1024;
    unsigned short* AL = adjPL + (size_t)(side * 256 + g) * 1024;
    for (int k = t; k < 1024; k += 512) {
      float v = A[k] * dinv[k >> 5] * dinv[k & 31];
      unsigned short h, l;
      split2(v, h, l);
      AH[k] = h;
      AL[k] = l;
    }
  } else {
    __shared__ float tile[32][33];
    int r = bx - 512;
    int z, x, y;
    if (r < 128)      { z = 0; x = r & 15; y = r >> 4; }
    else if (r < 192) { z = 1; r -= 128; x = r & 7; y = r >> 3; }
    else              { z = 2; r -= 192; x = r & 7; y = r >> 3; }
    const float* W = (z == 0) ? W0 : (z == 1) ? W1 : W2;
    const int K = (z == 0) ? 512 : 256;
    unsigned short* WH = WP + ((z == 0) ? 0 : (z == 1) ? 262144 : 393216);
    unsigned short* WL = WH + ((z == 0) ? 131072 : 65536);
    const int k0 = x * 32, n0 = y * 32;
    const int tr = t & 31, tc = t >> 5;
    for (int rr = tc; rr < 32; rr += 16)
      tile[rr][tr] = W[(size_t)(k0 + rr) * 256 + n0 + tr];
    __syncthreads();
    for (int rr = tc; rr < 32; rr += 16) {
      float v = tile[tr][rr];
      unsigned short h, l;
      split2(v, h, l);
      WH[(size_t)(n0 + rr) * K + k0 + tr] = h;
      WL[(size_t)(n0 + rr) * K + k0 + tr] = l;
    }
  }
}

// ---- gnn_k: per pair, 3x [GEMM -> agg -> sim] via MFMA; sims to global ----
__global__ __launch_bounds__(512, 2) void gnn_k(
    const float* __restrict__ xq, const float* __restrict__ xc,
    const unsigned short* __restrict__ WH0, const unsigned short* __restrict__ WL0,
    const unsigned short* __restrict__ WH1, const unsigned short* __restrict__ WL1,
    const unsigned short* __restrict__ WH2, const unsigned short* __restrict__ WL2,
    const unsigned short* __restrict__ adjPH, const unsigned short* __restrict__ adjPL,
    const float* __restrict__ b0, const float* __restrict__ b1,
    const float* __restrict__ b2,
    const float* __restrict__ delp, const float* __restrict__ insp,
    float* __restrict__ sims) {
  __shared__ __align__(16) unsigned short Pp[2][64 * 264];   // planes (l0 A-stage alias)
  __shared__ __align__(16) unsigned short YT[2][256 * 72];   // Y^T planes
  __shared__ float dq[32], dic[32];
  unsigned short* SA0 = &Pp[0][0];  // L0 A staging: [2 buf][64*40]
  unsigned short* SA1 = &Pp[1][0];

  const int b = blockIdx.x, t = threadIdx.x;
  const int wave = t >> 6, lane = t & 63;
  const int lrow = lane & 15, kgrp = lane >> 4;
  const int aside = wave >> 2;
  const int wcol = (wave & 3) * 64;

  short8 aAh[2], aAl[2];
#pragma unroll
  for (int mf = 0; mf < 2; ++mf) {
    const size_t base = (size_t)(aside * 256 + b) * 1024 + (mf * 16 + lrow) * 32 + kgrp * 8;
    aAh[mf] = *(const short8*)&adjPH[base];
    aAl[mf] = *(const short8*)&adjPL[base];
  }

  for (int l = 0; l < 3; ++l) {
    const unsigned short* WH = (l == 0) ? WH0 : (l == 1) ? WH1 : WH2;
    const unsigned short* WL = (l == 0) ? WL0 : (l == 1) ? WL1 : WL2;
    const float* bias = (l == 0) ? b0 : (l == 1) ? b1 : b2;

    f32x4 acc[4][2];
#pragma unroll
    for (int i = 0; i < 4; ++i)
#pragma unroll
      for (int j = 0; j < 2; ++j) acc[i][j] = (f32x4){0.f, 0.f, 0.f, 0.f};

    if (l == 0) {
      const int arow = t >> 3, aseg = t & 7;
      const float* Asrc = (arow < 32)
          ? (xq + (size_t)(b * 32 + arow) * 512)
          : (xc + (size_t)(b * 32 + (arow - 32)) * 512);
      float4 xv = *(const float4*)(Asrc + aseg * 4);
      short8 pbh[2], pbl[2];
#pragma unroll
      for (int nf = 0; nf < 2; ++nf) {
        const int row = wave * 32 + nf * 16 + lrow;
        pbh[nf] = *(const short8*)&WH[(size_t)row * 512 + kgrp * 8];
        pbl[nf] = *(const short8*)&WL[(size_t)row * 512 + kgrp * 8];
      }
      {
        ushort4 h, lo;
        split2(xv.x, h.x, lo.x); split2(xv.y, h.y, lo.y);
        split2(xv.z, h.z, lo.z); split2(xv.w, h.w, lo.w);
        *(ushort4*)&SA0[arow * 40 + aseg * 4] = h;
        *(ushort4*)&SA1[arow * 40 + aseg * 4] = lo;
      }
      __syncthreads();
      int buf = 0;
      for (int kt = 0; kt < 512; kt += 32) {
        const bool more = (kt + 32 < 512);
        float4 xn;
        if (more) xn = *(const float4*)(Asrc + kt + 32 + aseg * 4);
        short8 bh0 = pbh[0], bh1 = pbh[1];
        short8 bl0 = pbl[0], bl1 = pbl[1];
        if (more) {
#pragma unroll
          for (int nf = 0; nf < 2; ++nf) {
            const int row = wave * 32 + nf * 16 + lrow;
            pbh[nf] = *(const short8*)&WH[(size_t)row * 512 + kt + 32 + kgrp * 8];
            pbl[nf] = *(const short8*)&WL[(size_t)row * 512 + kt + 32 + kgrp * 8];
          }
        }
        short8 ah[4], al[4];
#pragma unroll
        for (int mf = 0; mf < 4; ++mf) {
          const int off = buf * 2560 + (mf * 16 + lrow) * 40 + kgrp * 8;
          ah[mf] = *(const short8*)&SA0[off];
          al[mf] = *(const short8*)&SA1[off];
        }
#pragma unroll
        for (int mf = 0; mf < 4; ++mf) {
          acc[mf][0] = __builtin_amdgcn_mfma_f32_16x16x32_bf16(ah[mf], bh0, acc[mf][0], 0, 0, 0);
          acc[mf][0] = __builtin_amdgcn_mfma_f32_16x16x32_bf16(ah[mf], bl0, acc[mf][0], 0, 0, 0);
          acc[mf][0] = __builtin_amdgcn_mfma_f32_16x16x32_bf16(al[mf], bh0, acc[mf][0], 0, 0, 0);
          acc[mf][1] = __builtin_amdgcn_mfma_f32_16x16x32_bf16(ah[mf], bh1, acc[mf][1], 0, 0, 0);
          acc[mf][1] = __builtin_amdgcn_mfma_f32_16x16x32_bf16(ah[mf], bl1, acc[mf][1], 0, 0, 0);
          acc[mf][1] = __builtin_amdgcn_mfma_f32_16x16x32_bf16(al[mf], bh1, acc[mf][1], 0, 0, 0);
        }
        if (more) {
          ushort4 h, lo;
          split2(xn.x, h.x, lo.x); split2(xn.y, h.y, lo.y);
          split2(xn.z, h.z, lo.z); split2(xn.w, h.w, lo.w);
          *(ushort4*)&SA0[(buf ^ 1) * 2560 + arow * 40 + aseg * 4] = h;
          *(ushort4*)&SA1[(buf ^ 1) * 2560 + arow * 40 + aseg * 4] = lo;
        }
        buf ^= 1;
        __syncthreads();
      }
    } else {
#pragma unroll
      for (int kt8 = 0; kt8 < 8; ++kt8) {
        const int kt = kt8 * 32;
        short8 ah[4], al[4];
#pragma unroll
        for (int mf = 0; mf < 4; ++mf) {
          const int off = (mf * 16 + lrow) * 264 + kt + kgrp * 8;
          ah[mf] = *(const short8*)&Pp[0][off];
          al[mf] = *(const short8*)&Pp[1][off];
        }
#pragma unroll
        for (int nf = 0; nf < 2; ++nf) {
          const int row = wave * 32 + nf * 16 + lrow;
          short8 bh = *(const short8*)&WH[(size_t)row * 256 + kt + kgrp * 8];
          short8 bl = *(const short8*)&WL[(size_t)row * 256 + kt + kgrp * 8];
#pragma unroll
          for (int mf = 0; mf < 4; ++mf) {
            acc[mf][nf] = __builtin_amdgcn_mfma_f32_16x16x32_bf16(ah[mf], bh, acc[mf][nf], 0, 0, 0);
            acc[mf][nf] = __builtin_amdgcn_mfma_f32_16x16x32_bf16(ah[mf], bl, acc[mf][nf], 0, 0, 0);
            acc[mf][nf] = __builtin_amdgcn_mfma_f32_16x16x32_bf16(al[mf], bh, acc[mf][nf], 0, 0, 0);
          }
        }
      }
      __syncthreads();
    }
    // epilogue: acc -> Y^T bf16 planes
#pragma unroll
    for (int mf = 0; mf < 4; ++mf)
#pragma unroll
      for (int nf = 0; nf < 2; ++nf) {
        const int col = wave * 32 + nf * 16 + lrow;
        ushort4 hv, lv;
        split2(acc[mf][nf][0], hv.x, lv.x);
        split2(acc[mf][nf][1], hv.y, lv.y);
        split2(acc[mf][nf][2], hv.z, lv.z);
        split2(acc[mf][nf][3], hv.w, lv.w);
        *(ushort4*)&YT[0][col * 72 + mf * 16 + kgrp * 4] = hv;
        *(ushort4*)&YT[1][col * 72 + mf * 16 + kgrp * 4] = lv;
      }
    __syncthreads();

    // agg via MFMA: P = Ahat @ Y + bias
    f32x4 pacc[2][4];
    float bv[4];
#pragma unroll
    for (int nf = 0; nf < 4; ++nf) {
      bv[nf] = bias[wcol + nf * 16 + lrow];
      const int ncol = wcol + nf * 16 + lrow;
      const int kb = aside * 32 + kgrp * 8;
      short8 bh = *(const short8*)&YT[0][ncol * 72 + kb];
      short8 bl = *(const short8*)&YT[1][ncol * 72 + kb];
#pragma unroll
      for (int mf = 0; mf < 2; ++mf) {
        f32x4 pa = (f32x4){0.f, 0.f, 0.f, 0.f};
        pa = __builtin_amdgcn_mfma_f32_16x16x32_bf16(aAh[mf], bh, pa, 0, 0, 0);
        pa = __builtin_amdgcn_mfma_f32_16x16x32_bf16(aAh[mf], bl, pa, 0, 0, 0);
        pa = __builtin_amdgcn_mfma_f32_16x16x32_bf16(aAl[mf], bh, pa, 0, 0, 0);
        pacc[mf][nf] = pa;
      }
    }
#pragma unroll
    for (int mf = 0; mf < 2; ++mf)
#pragma unroll
      for (int nf = 0; nf < 4; ++nf)
#pragma unroll
        for (int r = 0; r < 4; ++r) pacc[mf][nf][r] += bv[nf];

    // write pre-relu planes
#pragma unroll
    for (int mf = 0; mf < 2; ++mf)
#pragma unroll
      for (int nf = 0; nf < 4; ++nf)
#pragma unroll
        for (int r = 0; r < 4; ++r) {
          const int prow = aside * 32 + mf * 16 + kgrp * 4 + r;
          const int pcol = wcol + nf * 16 + lrow;
          unsigned short h, lo;
          split2(pacc[mf][nf][r], h, lo);
          Pp[0][prow * 264 + pcol] = h;
          Pp[1][prow * 264 + pcol] = lo;
        }
    __syncthreads();
    // del/ins dots from planes
    {
      const int row = t >> 3, sub = t & 7;
      const float* pvec = ((row < 32) ? delp : insp) + l * 256;
      float a = 0.f;
#pragma unroll 8
      for (int k = 0; k < 32; ++k) {
        int idx = sub + 8 * k;
        float x = bf2f(Pp[0][row * 264 + idx]) + bf2f(Pp[1][row * 264 + idx]);
        a = fmaf(x, pvec[idx], a);
      }
      a += __shfl_xor(a, 1);
      a += __shfl_xor(a, 2);
      a += __shfl_xor(a, 4);
      if ((t & 7) == 0) { if (row < 32) dq[row] = -a; else dic[row & 31] = -a; }
    }
    __syncthreads();
    // sim main via MFMA (waves 0-3) -> GLOBAL sims
    if (wave < 4) {
      const int mf = wave >> 1, nf = wave & 1;
      f32x4 sa = (f32x4){0.f, 0.f, 0.f, 0.f};
#pragma unroll
      for (int kt8 = 0; kt8 < 8; ++kt8) {
        const int kt = kt8 * 32;
        const int aoff = (mf * 16 + lrow) * 264 + kt + kgrp * 8;
        const int boff = (32 + nf * 16 + lrow) * 264 + kt + kgrp * 8;
        short8 ah = *(const short8*)&Pp[0][aoff];
        short8 al = *(const short8*)&Pp[1][aoff];
        short8 bh = *(const short8*)&Pp[0][boff];
        short8 bl = *(const short8*)&Pp[1][boff];
        sa = __builtin_amdgcn_mfma_f32_16x16x32_bf16(ah, bh, sa, 0, 0, 0);
        sa = __builtin_amdgcn_mfma_f32_16x16x32_bf16(ah, bl, sa, 0, 0, 0);
        sa = __builtin_amdgcn_mfma_f32_16x16x32_bf16(al, bh, sa, 0, 0, 0);
      }
      float* dst = sims + ((size_t)b * 3 + l) * 1024;
#pragma unroll
      for (int r = 0; r < 4; ++r) {
        const int m = mf * 16 + kgrp * 4 + r;
        const int n = nf * 16 + lrow;
        dst[m * 32 + n] = fminf(-sa[r], dq[m] + dic[n]);
      }
    }
    __syncthreads();
    // relu planes for next layer
    if (l < 2) {
#pragma unroll
      for (int mf = 0; mf < 2; ++mf)
#pragma unroll
        for (int nf = 0; nf < 4; ++nf)
#pragma unroll
          for (int r = 0; r < 4; ++r) {
            const int prow = aside * 32 + mf * 16 + kgrp * 4 + r;
            const int pcol = wcol + nf * 16 + lrow;
            unsigned short h, lo;
            split2(fmaxf(pacc[mf][nf][r], 0.f), h, lo);
            Pp[0][prow * 264 + pcol] = h;
            Pp[1][prow * 264 + pcol] = lo;
          }
      __syncthreads();
    }
  }
}

// ---- wave primitives for the LAP ------------------------------------------
template <int CTRL>
__device__ __forceinline__ float dpp_ror_min(float x) {
  int y = __builtin_amdgcn_update_dpp(0, __float_as_int(x), CTRL, 0xf, 0xf, true);
  return fminf(x, __int_as_float(y));
}
template <int CTRL>
__device__ __forceinline__ float dpp_ror_add(float x) {
  int y = __builtin_amdgcn_update_dpp(0, __float_as_int(x), CTRL, 0xf, 0xf, true);
  return x + __int_as_float(y);
}
__device__ __forceinline__ float rdlane_f(float x, int l) {
  return __int_as_float(__builtin_amdgcn_readlane(__float_as_int(x), l));
}
__device__ __forceinline__ float wave_min32(float x) {
  x = dpp_ror_min<0x121>(x);
  x = dpp_ror_min<0x122>(x);
  x = dpp_ror_min<0x124>(x);
  x = dpp_ror_min<0x128>(x);
  return fminf(rdlane_f(x, 0), rdlane_f(x, 16));
}

// ---- 32x32 Jonker-Volgenant (R6-proven): CR + RT + greedy + SAP -----------
__global__ __launch_bounds__(64) void lap_k(const float* __restrict__ sim,
                                            float* __restrict__ mcost) {
  __shared__ float Cl[1024];
  __shared__ float Cp[32][33];
  __shared__ float vl[32];
  const int lane = threadIdx.x;
  const float* src = sim + (size_t)blockIdx.x * 1024;
  for (int k = lane; k < 1024; k += 64) {
    float x = src[k];
    Cl[k] = x;
    Cp[k >> 5][k & 31] = x;
  }
  if (lane >= 32) return;

  float minv = LAP_INF;
  int imin = 0;
#pragma unroll
  for (int i = 0; i < 32; ++i) {
    float val = Cl[i * 32 + lane];
    if (val < minv) { minv = val; imin = i; }
  }
  float vj = minv;
  float u = 0.0f;
  int col4row = -1;
  int row4col = -1;
#pragma unroll
  for (int r = 0; r < 32; ++r) {
    unsigned long long bal = __ballot(imin == r);
    if (bal) {
      int j = 63 - __clzll(bal);
      if (lane == j) row4col = r;
      if (lane == r) col4row = j;
    }
  }
  unsigned long long freemask = __ballot(col4row < 0);

  vl[lane] = vj;
  __syncthreads();
  {
    float min1 = LAP_INF, min2 = LAP_INF;
    int j1 = -1;
#pragma unroll
    for (int j = 0; j < 32; ++j) {
      float s = Cp[lane][j] - vl[j];
      if (s < min1) { min2 = min1; min1 = s; j1 = j; }
      else if (s < min2) { min2 = s; }
    }
    float delta = 0.f;
    if (col4row >= 0) {
      delta = (j1 == col4row) ? min2 : min1;
      u = delta;
    }
    int sidx = (row4col < 0) ? lane : row4col;
    float dv = __shfl(delta, sidx);
    if (row4col >= 0) vj -= dv;
  }

  if (freemask) {
    __syncthreads();
    vl[lane] = vj;
    __syncthreads();
    float rs = LAP_INF;
#pragma unroll
    for (int j = 0; j < 32; ++j) rs = fminf(rs, Cp[lane][j] - vl[j]);
    if (col4row < 0) u = rs;
    unsigned long long fm = freemask;
    while (fm) {
      const int r = __ffsll(fm) - 1;
      fm &= fm - 1;
      float m = rdlane_f(rs, r);
      float s = Cl[r * 32 + lane] - vj;
      unsigned long long bal = __ballot((s == m) && (row4col < 0));
      if (bal) {
        int j = __ffsll(bal) - 1;
        if (lane == j) row4col = r;
        if (lane == r) col4row = j;
      }
    }
    freemask = __ballot(col4row < 0);
  }

  while (freemask) {
    const int cur = __ffsll(freemask) - 1;
    freemask &= freemask - 1;
    float shortest = LAP_INF;
    int path = -1;
    bool SC = false;
    int i = cur;
    float minval = 0.0f;
    int sink;
    while (true) {
      float ui = rdlane_f(u, i);
      float r = minval + Cl[i * 32 + lane] - ui - vj;
      bool better = (!SC) && (r < shortest);
      shortest = better ? r : shortest;
      path = better ? i : path;
      float masked = SC ? LAP_INF : shortest;
      float mv = wave_min32(masked);
      unsigned long long bal = __ballot(masked == mv);
      int j = __ffsll(bal) - 1;
      minval = mv;
      SC = SC || (lane == j);
      int rj = __builtin_amdgcn_readlane(row4col, j);
      if (rj < 0) { sink = j; break; }
      i = rj;
    }
    unsigned long long scmask = __ballot(SC);
    if (SC) vj -= minval - shortest;
    int sidx = (col4row < 0) ? lane : col4row;
    float sh_j0 = __shfl(shortest, sidx);
    bool scanned = (col4row >= 0) && ((scmask >> col4row) & 1ull) && (col4row != sink);
    if (lane == cur) u += minval;
    else if (scanned) u += minval - sh_j0;
    int j = sink;
    while (true) {
      int i2 = __builtin_amdgcn_readlane(path, j);
      int jn = __builtin_amdgcn_readlane(col4row, i2);
      if (lane == j) row4col = i2;
      if (lane == i2) col4row = j;
      j = jn;
      if (i2 == cur) break;
    }
  }
  float cc = Cl[lane * 32 + col4row];
  cc = dpp_ror_add<0x121>(cc);
  cc = dpp_ror_add<0x122>(cc);
  cc = dpp_ror_add<0x124>(cc);
  cc = dpp_ror_add<0x128>(cc);
  float tot = rdlane_f(cc, 0) + rdlane_f(cc, 16);
  if (lane == 0) mcost[blockIdx.x] = tot;
}

// ---- head: sigmoid(sum_l mcost/S * w_l + b) -------------------------------
__global__ void final_k(const float* __restrict__ mcost,
                        const float* __restrict__ ot_w,
                        const float* __restrict__ ot_b,
                        float* __restrict__ out) {
  int b = threadIdx.x;
  if (b < 256) {
    float s = ot_b[0];
#pragma unroll
    for (int l = 0; l < 3; ++l)
      s += mcost[b * 3 + l] * (1.0f / 32.0f) * ot_w[l];
    out[b] = 1.0f / (1.0f + expf(-s));
  }
}

extern "C" void kernel_launch(void* const* d_in, const int* in_sizes, int n_in,
                              void* d_out, int out_size, void* d_ws, size_t ws_size,
                              hipStream_t stream) {
  const float* x_q  = (const float*)d_in[0];
  const float* x_c  = (const float*)d_in[1];
  const float* W0   = (const float*)d_in[2];
  const float* b0   = (const float*)d_in[3];
  const float* W1   = (const float*)d_in[4];
  const float* b1   = (const float*)d_in[5];
  const float* W2   = (const float*)d_in[6];
  const float* b2   = (const float*)d_in[7];
  const float* delp = (const float*)d_in[8];
  const float* insp = (const float*)d_in[9];
  const float* ot_w = (const float*)d_in[10];
  const float* ot_b = (const float*)d_in[11];
  const int* ei_q   = (const int*)d_in[12];
  const int* ei_c   = (const int*)d_in[13];
  float* out = (float*)d_out;

  unsigned short* adjPH = (unsigned short*)d_ws;           // 524288 ushorts
  unsigned short* adjPL = adjPH + 524288;                  // 524288 ushorts
  unsigned short* WP = adjPL + 524288;                     // 524288 ushorts
  unsigned short* WH0 = WP;
  unsigned short* WL0 = WP + 131072;
  unsigned short* WH1 = WP + 262144;
  unsigned short* WL1 = WP + 327680;
  unsigned short* WH2 = WP + 393216;
  unsigned short* WL2 = WP + 458752;
  float* sims  = (float*)(WP + 524288);                    // 786432 floats
  float* mcost = sims + 786432;                            // 768 floats

  const int ne = in_sizes[12] / 2;   // directed edges per side (65536)

  prep_k<<<768, 512, 0, stream>>>(ei_q, ei_c, W0, W1, W2, adjPH, adjPL, WP, ne);
  gnn_k<<<256, 512, 0, stream>>>(x_q, x_c, WH0, WL0, WH1, WL1, WH2, WL2,
                                 adjPH, adjPL, b0, b1, b2, delp, insp, sims);
  lap_k<<<768, 64, 0, stream>>>(sims, mcost);
  final_k<<<1, 256, 0, stream>>>(mcost, ot_w, ot_b, out);
}

// Round 19
// 143.438 us; speedup vs baseline: 1.0627x; 1.0627x over previous
//
#include <hip/hip_runtime.h>
#include <math.h>

// ---------------------------------------------------------------------------
// GOTSim, fully fused: prep (adjacency bf16 planes + W planes) -> gnn_k:
// per pair, 3x [MFMA GEMM (pipelined) -> agg via MFMA -> sim via MFMA] in
// LDS, then 3 JV LAPs on waves 0-2 (packed-key argmin with embedded row4col:
// shorter Dijkstra chain + built-in free-column tie preference), sigmoid out.
// 2 dispatches. B=256, S=32, L=3, FIN=512, F=256.
// ---------------------------------------------------------------------------

#define LAP_INF 1e30f

typedef __attribute__((ext_vector_type(8))) short short8;
typedef __attribute__((ext_vector_type(4))) float f32x4;

__device__ __forceinline__ unsigned short bf16_rne(float x) {
  unsigned u = __float_as_uint(x);
  return (unsigned short)((u + 0x7fffu + ((u >> 16) & 1u)) >> 16);
}
__device__ __forceinline__ void split2(float x, unsigned short& h, unsigned short& l) {
  h = bf16_rne(x);
  l = (unsigned short)(__float_as_uint(x - __uint_as_float((unsigned)h << 16)) >> 16);
}
__device__ __forceinline__ float bf2f(unsigned short u) {
  return __uint_as_float((unsigned)u << 16);
}

// ---- prep: per-graph adjacency bf16 hi/lo planes + W bf16 planes ----------
__global__ __launch_bounds__(512) void prep_k(const int* __restrict__ eiq,
                                              const int* __restrict__ eic,
                                              const float* __restrict__ W0,
                                              const float* __restrict__ W1,
                                              const float* __restrict__ W2,
                                              unsigned short* __restrict__ adjPH,
                                              unsigned short* __restrict__ adjPL,
                                              unsigned short* __restrict__ WP,
                                              int ne) {
  const int bx = blockIdx.x;
  const int t = threadIdx.x;
  if (bx < 512) {
    __shared__ float A[1024];
    __shared__ float dinv[32];
    const int g = bx & 255, side = bx >> 8;
    const int* ei = side ? eic : eiq;
    const int half = ne >> 1;
    for (int k = t; k < 1024; k += 512) A[k] = 0.f;
    __syncthreads();
    if (t < 256) {
      int e = (t < 128) ? (g * 128 + t) : (half + g * 128 + (t - 128));
      int s = ei[e];
      int d = ei[ne + e];
      if ((d >> 5) == g)
        atomicAdd(&A[(d & 31) * 32 + (s & 31)], 1.0f);
    }
    __syncthreads();
    if (t < 32) A[t * 32 + t] += 1.0f;
    __syncthreads();
    if (t < 32) {
      float dsum = 0.f;
#pragma unroll
      for (int j = 0; j < 32; ++j) dsum += A[t * 32 + j];
      dinv[t] = rsqrtf(dsum);
    }
    __syncthreads();
    unsigned short* AH = adjPH + (size_t)(side * 256 + g) * 1024;
    unsigned short* AL = adjPL + (size_t)(side * 256 + g) * 1024;
    for (int k = t; k < 1024; k += 512) {
      float v = A[k] * dinv[k >> 5] * dinv[k & 31];
      unsigned short h, l;
      split2(v, h, l);
      AH[k] = h;
      AL[k] = l;
    }
  } else {
    __shared__ float tile[32][33];
    int r = bx - 512;
    int z, x, y;
    if (r < 128)      { z = 0; x = r & 15; y = r >> 4; }
    else if (r < 192) { z = 1; r -= 128; x = r & 7; y = r >> 3; }
    else              { z = 2; r -= 192; x = r & 7; y = r >> 3; }
    const float* W = (z == 0) ? W0 : (z == 1) ? W1 : W2;
    const int K = (z == 0) ? 512 : 256;
    unsigned short* WH = WP + ((z == 0) ? 0 : (z == 1) ? 262144 : 393216);
    unsigned short* WL = WH + ((z == 0) ? 131072 : 65536);
    const int k0 = x * 32, n0 = y * 32;
    const int tr = t & 31, tc = t >> 5;
    for (int rr = tc; rr < 32; rr += 16)
      tile[rr][tr] = W[(size_t)(k0 + rr) * 256 + n0 + tr];
    __syncthreads();
    for (int rr = tc; rr < 32; rr += 16) {
      float v = tile[tr][rr];
      unsigned short h, l;
      split2(v, h, l);
      WH[(size_t)(n0 + rr) * K + k0 + tr] = h;
      WL[(size_t)(n0 + rr) * K + k0 + tr] = l;
    }
  }
}

// ---- wave primitives for the LAP ------------------------------------------
template <int CTRL>
__device__ __forceinline__ float dpp_ror_min(float x) {
  int y = __builtin_amdgcn_update_dpp(0, __float_as_int(x), CTRL, 0xf, 0xf, true);
  return fminf(x, __int_as_float(y));
}
template <int CTRL>
__device__ __forceinline__ float dpp_ror_add(float x) {
  int y = __builtin_amdgcn_update_dpp(0, __float_as_int(x), CTRL, 0xf, 0xf, true);
  return x + __int_as_float(y);
}
template <int CTRL>
__device__ __forceinline__ unsigned dpp_ror_minu(unsigned x) {
  unsigned y = (unsigned)__builtin_amdgcn_update_dpp(0, (int)x, CTRL, 0xf, 0xf, true);
  return x < y ? x : y;
}
__device__ __forceinline__ float rdlane_f(float x, int l) {
  return __int_as_float(__builtin_amdgcn_readlane(__float_as_int(x), l));
}
__device__ __forceinline__ float wave_min32(float x) {
  x = dpp_ror_min<0x121>(x);
  x = dpp_ror_min<0x122>(x);
  x = dpp_ror_min<0x124>(x);
  x = dpp_ror_min<0x128>(x);
  return fminf(rdlane_f(x, 0), rdlane_f(x, 16));
}
#define LDS_FENCE() __asm__ volatile("s_waitcnt lgkmcnt(0)" ::: "memory")

// ---- fully fused per-pair kernel ------------------------------------------
__global__ __launch_bounds__(512, 2) void gnn_k(
    const float* __restrict__ xq, const float* __restrict__ xc,
    const unsigned short* __restrict__ WH0, const unsigned short* __restrict__ WL0,
    const unsigned short* __restrict__ WH1, const unsigned short* __restrict__ WL1,
    const unsigned short* __restrict__ WH2, const unsigned short* __restrict__ WL2,
    const unsigned short* __restrict__ adjPH, const unsigned short* __restrict__ adjPL,
    const float* __restrict__ b0, const float* __restrict__ b1,
    const float* __restrict__ b2,
    const float* __restrict__ delp, const float* __restrict__ insp,
    const float* __restrict__ ot_w, const float* __restrict__ ot_b,
    float* __restrict__ out) {
  __shared__ __align__(16) unsigned short Pp[2][64 * 264];   // planes (l0 A-stage alias)
  __shared__ __align__(16) unsigned short YT[2][256 * 72];   // Y^T planes
  __shared__ __align__(16) float simsbuf[3][1024];
  __shared__ float dq[32], dic[32];
  __shared__ float mc[4];
  unsigned short* SA0 = &Pp[0][0];  // L0 A staging: [2 buf][64*40]
  unsigned short* SA1 = &Pp[1][0];

  const int b = blockIdx.x, t = threadIdx.x;
  const int wave = t >> 6, lane = t & 63;
  const int lrow = lane & 15, kgrp = lane >> 4;
  const int aside = wave >> 2;
  const int wcol = (wave & 3) * 64;

  short8 aAh[2], aAl[2];
#pragma unroll
  for (int mf = 0; mf < 2; ++mf) {
    const size_t base = (size_t)(aside * 256 + b) * 1024 + (mf * 16 + lrow) * 32 + kgrp * 8;
    aAh[mf] = *(const short8*)&adjPH[base];
    aAl[mf] = *(const short8*)&adjPL[base];
  }

  for (int l = 0; l < 3; ++l) {
    const unsigned short* WH = (l == 0) ? WH0 : (l == 1) ? WH1 : WH2;
    const unsigned short* WL = (l == 0) ? WL0 : (l == 1) ? WL1 : WL2;
    const float* bias = (l == 0) ? b0 : (l == 1) ? b1 : b2;

    f32x4 acc[4][2];
#pragma unroll
    for (int i = 0; i < 4; ++i)
#pragma unroll
      for (int j = 0; j < 2; ++j) acc[i][j] = (f32x4){0.f, 0.f, 0.f, 0.f};

    if (l == 0) {
      const int arow = t >> 3, aseg = t & 7;
      const float* Asrc = (arow < 32)
          ? (xq + (size_t)(b * 32 + arow) * 512)
          : (xc + (size_t)(b * 32 + (arow - 32)) * 512);
      float4 xv = *(const float4*)(Asrc + aseg * 4);
      short8 pbh[2], pbl[2];
#pragma unroll
      for (int nf = 0; nf < 2; ++nf) {
        const int row = wave * 32 + nf * 16 + lrow;
        pbh[nf] = *(const short8*)&WH[(size_t)row * 512 + kgrp * 8];
        pbl[nf] = *(const short8*)&WL[(size_t)row * 512 + kgrp * 8];
      }
      {
        ushort4 h, lo;
        split2(xv.x, h.x, lo.x); split2(xv.y, h.y, lo.y);
        split2(xv.z, h.z, lo.z); split2(xv.w, h.w, lo.w);
        *(ushort4*)&SA0[arow * 40 + aseg * 4] = h;
        *(ushort4*)&SA1[arow * 40 + aseg * 4] = lo;
      }
      __syncthreads();
      int buf = 0;
      for (int kt = 0; kt < 512; kt += 32) {
        const bool more = (kt + 32 < 512);
        float4 xn;
        if (more) xn = *(const float4*)(Asrc + kt + 32 + aseg * 4);
        short8 bh0 = pbh[0], bh1 = pbh[1];
        short8 bl0 = pbl[0], bl1 = pbl[1];
        if (more) {
#pragma unroll
          for (int nf = 0; nf < 2; ++nf) {
            const int row = wave * 32 + nf * 16 + lrow;
            pbh[nf] = *(const short8*)&WH[(size_t)row * 512 + kt + 32 + kgrp * 8];
            pbl[nf] = *(const short8*)&WL[(size_t)row * 512 + kt + 32 + kgrp * 8];
          }
        }
        short8 ah[4], al[4];
#pragma unroll
        for (int mf = 0; mf < 4; ++mf) {
          const int off = buf * 2560 + (mf * 16 + lrow) * 40 + kgrp * 8;
          ah[mf] = *(const short8*)&SA0[off];
          al[mf] = *(const short8*)&SA1[off];
        }
#pragma unroll
        for (int mf = 0; mf < 4; ++mf) {
          acc[mf][0] = __builtin_amdgcn_mfma_f32_16x16x32_bf16(ah[mf], bh0, acc[mf][0], 0, 0, 0);
          acc[mf][0] = __builtin_amdgcn_mfma_f32_16x16x32_bf16(ah[mf], bl0, acc[mf][0], 0, 0, 0);
          acc[mf][0] = __builtin_amdgcn_mfma_f32_16x16x32_bf16(al[mf], bh0, acc[mf][0], 0, 0, 0);
          acc[mf][1] = __builtin_amdgcn_mfma_f32_16x16x32_bf16(ah[mf], bh1, acc[mf][1], 0, 0, 0);
          acc[mf][1] = __builtin_amdgcn_mfma_f32_16x16x32_bf16(ah[mf], bl1, acc[mf][1], 0, 0, 0);
          acc[mf][1] = __builtin_amdgcn_mfma_f32_16x16x32_bf16(al[mf], bh1, acc[mf][1], 0, 0, 0);
        }
        if (more) {
          ushort4 h, lo;
          split2(xn.x, h.x, lo.x); split2(xn.y, h.y, lo.y);
          split2(xn.z, h.z, lo.z); split2(xn.w, h.w, lo.w);
          *(ushort4*)&SA0[(buf ^ 1) * 2560 + arow * 40 + aseg * 4] = h;
          *(ushort4*)&SA1[(buf ^ 1) * 2560 + arow * 40 + aseg * 4] = lo;
        }
        buf ^= 1;
        __syncthreads();
      }
    } else {
#pragma unroll
      for (int kt8 = 0; kt8 < 8; ++kt8) {
        const int kt = kt8 * 32;
        short8 ah[4], al[4];
#pragma unroll
        for (int mf = 0; mf < 4; ++mf) {
          const int off = (mf * 16 + lrow) * 264 + kt + kgrp * 8;
          ah[mf] = *(const short8*)&Pp[0][off];
          al[mf] = *(const short8*)&Pp[1][off];
        }
#pragma unroll
        for (int nf = 0; nf < 2; ++nf) {
          const int row = wave * 32 + nf * 16 + lrow;
          short8 bh = *(const short8*)&WH[(size_t)row * 256 + kt + kgrp * 8];
          short8 bl = *(const short8*)&WL[(size_t)row * 256 + kt + kgrp * 8];
#pragma unroll
          for (int mf = 0; mf < 4; ++mf) {
            acc[mf][nf] = __builtin_amdgcn_mfma_f32_16x16x32_bf16(ah[mf], bh, acc[mf][nf], 0, 0, 0);
            acc[mf][nf] = __builtin_amdgcn_mfma_f32_16x16x32_bf16(ah[mf], bl, acc[mf][nf], 0, 0, 0);
            acc[mf][nf] = __builtin_amdgcn_mfma_f32_16x16x32_bf16(al[mf], bh, acc[mf][nf], 0, 0, 0);
          }
        }
      }
      __syncthreads();
    }
    // epilogue: acc -> Y^T bf16 planes
#pragma unroll
    for (int mf = 0; mf < 4; ++mf)
#pragma unroll
      for (int nf = 0; nf < 2; ++nf) {
        const int col = wave * 32 + nf * 16 + lrow;
        ushort4 hv, lv;
        split2(acc[mf][nf][0], hv.x, lv.x);
        split2(acc[mf][nf][1], hv.y, lv.y);
        split2(acc[mf][nf][2], hv.z, lv.z);
        split2(acc[mf][nf][3], hv.w, lv.w);
        *(ushort4*)&YT[0][col * 72 + mf * 16 + kgrp * 4] = hv;
        *(ushort4*)&YT[1][col * 72 + mf * 16 + kgrp * 4] = lv;
      }
    __syncthreads();

    // agg via MFMA: P = Ahat @ Y + bias
    f32x4 pacc[2][4];
    float bv[4];
#pragma unroll
    for (int nf = 0; nf < 4; ++nf) {
      bv[nf] = bias[wcol + nf * 16 + lrow];
      const int ncol = wcol + nf * 16 + lrow;
      const int kb = aside * 32 + kgrp * 8;
      short8 bh = *(const short8*)&YT[0][ncol * 72 + kb];
      short8 bl = *(const short8*)&YT[1][ncol * 72 + kb];
#pragma unroll
      for (int mf = 0; mf < 2; ++mf) {
        f32x4 pa = (f32x4){0.f, 0.f, 0.f, 0.f};
        pa = __builtin_amdgcn_mfma_f32_16x16x32_bf16(aAh[mf], bh, pa, 0, 0, 0);
        pa = __builtin_amdgcn_mfma_f32_16x16x32_bf16(aAh[mf], bl, pa, 0, 0, 0);
        pa = __builtin_amdgcn_mfma_f32_16x16x32_bf16(aAl[mf], bh, pa, 0, 0, 0);
        pacc[mf][nf] = pa;
      }
    }
#pragma unroll
    for (int mf = 0; mf < 2; ++mf)
#pragma unroll
      for (int nf = 0; nf < 4; ++nf)
#pragma unroll
        for (int r = 0; r < 4; ++r) pacc[mf][nf][r] += bv[nf];

    // write pre-relu planes
#pragma unroll
    for (int mf = 0; mf < 2; ++mf)
#pragma unroll
      for (int nf = 0; nf < 4; ++nf)
#pragma unroll
        for (int r = 0; r < 4; ++r) {
          const int prow = aside * 32 + mf * 16 + kgrp * 4 + r;
          const int pcol = wcol + nf * 16 + lrow;
          unsigned short h, lo;
          split2(pacc[mf][nf][r], h, lo);
          Pp[0][prow * 264 + pcol] = h;
          Pp[1][prow * 264 + pcol] = lo;
        }
    __syncthreads();
    // del/ins dots from planes
    {
      const int row = t >> 3, sub = t & 7;
      const float* pvec = ((row < 32) ? delp : insp) + l * 256;
      float a = 0.f;
#pragma unroll 8
      for (int k = 0; k < 32; ++k) {
        int idx = sub + 8 * k;
        float x = bf2f(Pp[0][row * 264 + idx]) + bf2f(Pp[1][row * 264 + idx]);
        a = fmaf(x, pvec[idx], a);
      }
      a += __shfl_xor(a, 1);
      a += __shfl_xor(a, 2);
      a += __shfl_xor(a, 4);
      if ((t & 7) == 0) { if (row < 32) dq[row] = -a; else dic[row & 31] = -a; }
    }
    __syncthreads();
    // sim main via MFMA (waves 0-3)
    if (wave < 4) {
      const int mf = wave >> 1, nf = wave & 1;
      f32x4 sa = (f32x4){0.f, 0.f, 0.f, 0.f};
#pragma unroll
      for (int kt8 = 0; kt8 < 8; ++kt8) {
        const int kt = kt8 * 32;
        const int aoff = (mf * 16 + lrow) * 264 + kt + kgrp * 8;
        const int boff = (32 + nf * 16 + lrow) * 264 + kt + kgrp * 8;
        short8 ah = *(const short8*)&Pp[0][aoff];
        short8 al = *(const short8*)&Pp[1][aoff];
        short8 bh = *(const short8*)&Pp[0][boff];
        short8 bl = *(const short8*)&Pp[1][boff];
        sa = __builtin_amdgcn_mfma_f32_16x16x32_bf16(ah, bh, sa, 0, 0, 0);
        sa = __builtin_amdgcn_mfma_f32_16x16x32_bf16(ah, bl, sa, 0, 0, 0);
        sa = __builtin_amdgcn_mfma_f32_16x16x32_bf16(al, bh, sa, 0, 0, 0);
      }
#pragma unroll
      for (int r = 0; r < 4; ++r) {
        const int m = mf * 16 + kgrp * 4 + r;
        const int n = nf * 16 + lrow;
        simsbuf[l][m * 32 + n] = fminf(-sa[r], dq[m] + dic[n]);
      }
    }
    __syncthreads();
    // relu planes for next layer
    if (l < 2) {
#pragma unroll
      for (int mf = 0; mf < 2; ++mf)
#pragma unroll
        for (int nf = 0; nf < 4; ++nf)
#pragma unroll
          for (int r = 0; r < 4; ++r) {
            const int prow = aside * 32 + mf * 16 + kgrp * 4 + r;
            const int pcol = wcol + nf * 16 + lrow;
            unsigned short h, lo;
            split2(fmaxf(pacc[mf][nf][r], 0.f), h, lo);
            Pp[0][prow * 264 + pcol] = h;
            Pp[1][prow * 264 + pcol] = lo;
          }
      __syncthreads();
    }
  }

  // ---- 3 JV LAPs on waves 0-2; packed-key argmin with embedded row4col ----
  if (wave < 3) {
    if (lane < 32) {
      float* Cl = &simsbuf[wave][0];
      float vlreg;
      float minv = LAP_INF;
      int imin = 0;
#pragma unroll
      for (int i = 0; i < 32; ++i) {
        float val = Cl[i * 32 + lane];
        if (val < minv) { minv = val; imin = i; }
      }
      float vj = minv;
      float u = 0.0f;
      int col4row = -1;
      int row4col = -1;
#pragma unroll
      for (int r = 0; r < 32; ++r) {
        unsigned long long bal = __ballot(imin == r);
        if (bal) {
          int j = 63 - __clzll(bal);
          if (lane == j) row4col = r;
          if (lane == r) col4row = j;
        }
      }
      unsigned long long freemask = __ballot(col4row < 0);

      // parallel reduction transfer (old duals); vl via shfl (no LDS needed)
      {
        float min1 = LAP_INF, min2 = LAP_INF;
        int j1 = -1;
#pragma unroll
        for (int j = 0; j < 32; ++j) {
          float s = Cl[lane * 32 + j] - __shfl(vj, j);
          if (s < min1) { min2 = min1; min1 = s; j1 = j; }
          else if (s < min2) { min2 = s; }
        }
        float delta = 0.f;
        if (col4row >= 0) {
          delta = (j1 == col4row) ? min2 : min1;
          u = delta;
        }
        int sidx = (row4col < 0) ? lane : row4col;
        float dv = __shfl(delta, sidx);
        if (row4col >= 0) vj -= dv;
      }

      // zero-arc greedy for free rows
      if (freemask) {
        float rs = LAP_INF;
#pragma unroll
        for (int j = 0; j < 32; ++j) rs = fminf(rs, Cl[lane * 32 + j] - __shfl(vj, j));
        if (col4row < 0) u = rs;
        unsigned long long fm = freemask;
        while (fm) {
          const int r = __ffsll(fm) - 1;
          fm &= fm - 1;
          float m = rdlane_f(rs, r);
          float s = Cl[r * 32 + lane] - vj;
          unsigned long long bal = __ballot((s == m) && (row4col < 0));
          if (bal) {
            int j = __ffsll(bal) - 1;
            if (lane == j) row4col = r;
            if (lane == r) col4row = j;
          }
        }
        freemask = __ballot(col4row < 0);
      }

      // SAP: packed key = dist[31:11] | (row4col+1)<<5 | lane
      //  - argmin + popped column's row in ONE reduction
      //  - free cols (row4col+1 == 0) win near-ties -> early termination
      //  - minval recovered exactly via readlane (duals stay consistent)
      while (freemask) {
        const int cur = __ffsll(freemask) - 1;
        freemask &= freemask - 1;
        float shortest = LAP_INF;
        int path = -1;
        bool SC = false;
        int i = cur;
        float minval = 0.0f;
        int sink;
        while (true) {
          float ci = Cl[i * 32 + lane];
          float ui = rdlane_f(u, i);
          float r = (minval - ui) + ci - vj;
          bool better = (!SC) && (r < shortest);
          shortest = better ? r : shortest;
          path = better ? i : path;
          float masked = SC ? LAP_INF : shortest;
          unsigned bu = __float_as_uint(masked);
          unsigned su = (bu & 0x80000000u) ? ~bu : (bu | 0x80000000u);
          unsigned key = (su & 0xFFFFF800u) | ((unsigned)(row4col + 1) << 5) | (unsigned)lane;
          key = dpp_ror_minu<0x121>(key);
          key = dpp_ror_minu<0x122>(key);
          key = dpp_ror_minu<0x124>(key);
          key = dpp_ror_minu<0x128>(key);
          unsigned k0 = (unsigned)__builtin_amdgcn_readlane((int)key, 0);
          unsigned k1 = (unsigned)__builtin_amdgcn_readlane((int)key, 16);
          unsigned km = k0 < k1 ? k0 : k1;
          int j = (int)(km & 31u);
          int rj = (int)((km >> 5) & 63u) - 1;
          minval = rdlane_f(masked, j);
          SC = SC || (lane == j);
          if (rj < 0) { sink = j; break; }
          i = rj;
        }
        unsigned long long scmask = __ballot(SC);
        if (SC) vj -= minval - shortest;
        int sidx = (col4row < 0) ? lane : col4row;
        float sh_j0 = __shfl(shortest, sidx);
        bool scanned = (col4row >= 0) && ((scmask >> col4row) & 1ull) && (col4row != sink);
        if (lane == cur) u += minval;
        else if (scanned) u += minval - sh_j0;
        int j = sink;
        while (true) {
          int i2 = __builtin_amdgcn_readlane(path, j);
          int jn = __builtin_amdgcn_readlane(col4row, i2);
          if (lane == j) row4col = i2;
          if (lane == i2) col4row = j;
          j = jn;
          if (i2 == cur) break;
        }
      }
      float cc = Cl[lane * 32 + col4row];
      cc = dpp_ror_add<0x121>(cc);
      cc = dpp_ror_add<0x122>(cc);
      cc = dpp_ror_add<0x124>(cc);
      cc = dpp_ror_add<0x128>(cc);
      float tot = rdlane_f(cc, 0) + rdlane_f(cc, 16);
      if (lane == 0) mc[wave] = tot;
      (void)vlreg;
    }
  }
  __syncthreads();
  if (t == 0) {
    float s = ot_b[0];
#pragma unroll
    for (int l2 = 0; l2 < 3; ++l2)
      s += mc[l2] * (1.0f / 32.0f) * ot_w[l2];
    out[b] = 1.0f / (1.0f + expf(-s));
  }
}

extern "C" void kernel_launch(void* const* d_in, const int* in_sizes, int n_in,
                              void* d_out, int out_size, void* d_ws, size_t ws_size,
                              hipStream_t stream) {
  const float* x_q  = (const float*)d_in[0];
  const float* x_c  = (const float*)d_in[1];
  const float* W0   = (const float*)d_in[2];
  const float* b0   = (const float*)d_in[3];
  const float* W1   = (const float*)d_in[4];
  const float* b1   = (const float*)d_in[5];
  const float* W2   = (const float*)d_in[6];
  const float* b2   = (const float*)d_in[7];
  const float* delp = (const float*)d_in[8];
  const float* insp = (const float*)d_in[9];
  const float* ot_w = (const float*)d_in[10];
  const float* ot_b = (const float*)d_in[11];
  const int* ei_q   = (const int*)d_in[12];
  const int* ei_c   = (const int*)d_in[13];
  float* out = (float*)d_out;

  unsigned short* adjPH = (unsigned short*)d_ws;           // 524288 ushorts
  unsigned short* adjPL = adjPH + 524288;                  // 524288 ushorts
  unsigned short* WP = adjPL + 524288;                     // 524288 ushorts
  unsigned short* WH0 = WP;
  unsigned short* WL0 = WP + 131072;
  unsigned short* WH1 = WP + 262144;
  unsigned short* WL1 = WP + 327680;
  unsigned short* WH2 = WP + 393216;
  unsigned short* WL2 = WP + 458752;

  const int ne = in_sizes[12] / 2;   // directed edges per side (65536)

  prep_k<<<768, 512, 0, stream>>>(ei_q, ei_c, W0, W1, W2, adjPH, adjPL, WP, ne);
  gnn_k<<<256, 512, 0, stream>>>(x_q, x_c, WH0, WL0, WH1, WL1, WH2, WL2,
                                 adjPH, adjPL, b0, b1, b2, delp, insp,
                                 ot_w, ot_b, out);
}